// Round 4
// baseline (989.345 us; speedup 1.0000x reference)
//
#include <hip/hip_runtime.h>

#define NSEG 128
#define BB 2
#define CC 768
#define CC4 (CC/4)          // 192 channel quads
#define HP 28
#define WP 28
#define HI 392
#define WI 392
#define NPIX (HI*WI)        // 153664
#define NPIX4 (NPIX/4)      // 38416
#define CPB4 16             // channel-quads per paint block (64 channels, 32 KB table slice)

typedef float f32x4 __attribute__((ext_vector_type(4)));   // native vector for nontemporal store

// Pack clamped segment ids to uint8, 4 pixels/thread.
__global__ void pid_kernel(const int* __restrict__ mask, unsigned int* __restrict__ sb) {
    int g = blockIdx.x * blockDim.x + threadIdx.x;
    if (g >= BB * NPIX4) return;
    int4 m = ((const int4*)mask)[g];
    unsigned int s0 = (unsigned int)min(max(m.x, 0), NSEG - 1);
    unsigned int s1 = (unsigned int)min(max(m.y, 0), NSEG - 1);
    unsigned int s2 = (unsigned int)min(max(m.z, 0), NSEG - 1);
    unsigned int s3 = (unsigned int)min(max(m.w, 0), NSEG - 1);
    sb[g] = s0 | (s1 << 8) | (s2 << 16) | (s3 << 24);
}

// One block per patch cell; accumulate feature vector into transposed sums[b][c][s].
__global__ void accum_kernel(const float* __restrict__ F, const int* __restrict__ mask,
                             float* __restrict__ sums, float* __restrict__ counts) {
    int cell = blockIdx.x;                   // 0 .. BB*HP*WP-1
    int b = cell / (HP * WP);
    int rem = cell - b * (HP * WP);
    int hp = rem / WP;
    int wp = rem - hp * WP;
    // ih = hp*HI/HP = hp*14 exactly; iw = wp*14
    int m = mask[(size_t)b * NPIX + (hp * 14) * WI + (wp * 14)];
    int s = min(max(m, 0), NSEG - 1);
    for (int c = threadIdx.x; c < CC; c += blockDim.x) {
        float v = F[((b * CC + c) * HP + hp) * WP + wp];
        atomicAdd(&sums[(size_t)(b * CC + c) * NSEG + s], v);
    }
    if (threadIdx.x == 0) atomicAdd(&counts[b * NSEG + s], 1.0f);
}

// In-place: convert channel-quad (4c4..4c4+3) sums into interleaved float4
// averages occupying the SAME 2 KB region. One block per (b, c4); read all four
// channels into registers, sync, write back interleaved. No extra workspace.
__global__ __launch_bounds__(128) void div_kernel(float* __restrict__ sums,
                                                  const float* __restrict__ counts) {
    int quad = blockIdx.x;                   // 0 .. BB*CC4-1
    int b = quad / CC4;
    int s = threadIdx.x;                     // 0..127
    float* base = sums + ((size_t)quad << 9);        // quad*4*NSEG floats (2 KB)
    float cnt = counts[b * NSEG + s];
    float v0 = base[s];
    float v1 = base[s + NSEG];
    float v2 = base[s + 2 * NSEG];
    float v3 = base[s + 3 * NSEG];
    float inv = (cnt > 0.0f) ? (1.0f / cnt) : 0.0f;
    __syncthreads();
    ((f32x4*)base)[s] = (f32x4){v0 * inv, v1 * inv, v2 * inv, v3 * inv};
}

// Paint: each thread owns 4 consecutive pixels; per iteration it serves 4 channels
// via 4 float4 table gathers (1 gather instr per channel — halved again vs float2)
// and 4 nontemporal float4 stores. Per-block table slice = 32 KiB.
__global__ __launch_bounds__(256) void paint_kernel(const f32x4* __restrict__ avg4,
                                                    const unsigned int* __restrict__ sb,
                                                    float* __restrict__ out) {
    int b = blockIdx.z;
    int g = blockIdx.x * blockDim.x + threadIdx.x;   // float4 pixel group within batch
    if (g >= NPIX4) return;
    unsigned int packed = sb[(size_t)b * NPIX4 + g];
    int s0 = packed & 255;
    int s1 = (packed >> 8) & 255;
    int s2 = (packed >> 16) & 255;
    int s3 = (packed >> 24) & 255;
    int q0 = blockIdx.y * CPB4;                      // channel-quad base
    const f32x4* tbl = avg4 + ((size_t)(b * CC4 + q0) << 7);
    f32x4* outp = (f32x4*)out + (size_t)(b * CC + 4 * q0) * NPIX4 + g;
    #pragma unroll 4
    for (int i = 0; i < CPB4; ++i) {
        const f32x4* t = tbl + ((size_t)i << 7);
        f32x4 a = t[s0], bb = t[s1], c = t[s2], d = t[s3];
        // transpose: output channel j gets {a[j], bb[j], c[j], d[j]} for pixels 0..3
        #pragma unroll
        for (int j = 0; j < 4; ++j) {
            f32x4 v = {a[j], bb[j], c[j], d[j]};
            __builtin_nontemporal_store(v, outp + (size_t)(4 * i + j) * NPIX4);
        }
    }
}

extern "C" void kernel_launch(void* const* d_in, const int* in_sizes, int n_in,
                              void* d_out, int out_size, void* d_ws, size_t ws_size,
                              hipStream_t stream) {
    const float* F = (const float*)d_in[0];
    const int* mask = (const int*)d_in[1];
    float* out = (float*)d_out;

    float* sums = (float*)d_ws;                            // BB*CC*NSEG floats (786,432 B)
    float* counts = sums + BB * CC * NSEG;                 // BB*NSEG floats (1,024 B)
    unsigned int* sb = (unsigned int*)(counts + BB * NSEG);// BB*NPIX4 words (307,328 B)
    // Total workspace: 1,094,784 B — identical footprint to the verified baseline.

    // Zero sums + counts (ws is poisoned each call).
    (void)hipMemsetAsync(d_ws, 0, (size_t)(BB * CC * NSEG + BB * NSEG) * sizeof(float), stream);

    int ngroups = BB * NPIX4;                                   // 76,832
    pid_kernel<<<(ngroups + 255) / 256, 256, 0, stream>>>(mask, sb);
    accum_kernel<<<BB * HP * WP, 256, 0, stream>>>(F, mask, sums, counts);
    div_kernel<<<BB * CC4, 128, 0, stream>>>(sums, counts);
    paint_kernel<<<dim3((NPIX4 + 255) / 256, CC4 / CPB4, BB), 256, 0, stream>>>(
        (const f32x4*)sums, sb, out);
}